// Round 2
// baseline (307.023 us; speedup 1.0000x reference)
//
#include <hip/hip_runtime.h>
#include <hip/hip_bf16.h>
#include <math.h>

typedef __attribute__((ext_vector_type(4))) float f32x4;
typedef __attribute__((ext_vector_type(8))) short bf16x8;

#define DEVI __device__ __forceinline__
#define GLBP(p) ((const __attribute__((address_space(1))) void*)(p))
#define LDSP(p) ((__attribute__((address_space(3))) void*)(p))

DEVI unsigned short f2b(float x) {
    __hip_bfloat16 b = __float2bfloat16(x);
    return *reinterpret_cast<unsigned short*>(&b);
}

// ---------------- cast f32 -> bf16, vectorized ----------------
__global__ void cast_f32_to_bf16(const float* __restrict__ in,
                                 unsigned short* __restrict__ out, int n) {
    int stride = gridDim.x * blockDim.x;
    for (int i = blockIdx.x * blockDim.x + threadIdx.x; i * 4 < n; i += stride) {
        float4 v = reinterpret_cast<const float4*>(in)[i];
        ushort4 o;
        o.x = f2b(v.x); o.y = f2b(v.y); o.z = f2b(v.z); o.w = f2b(v.w);
        reinterpret_cast<ushort4*>(out)[i] = o;
    }
}

// ------------- transpose+cast: f32 [R][C] -> bf16 [C][R] -------------
__global__ void transpose_cast(const float* __restrict__ in,
                               unsigned short* __restrict__ out, int R, int C) {
    __shared__ float t[32][33];
    int bc = blockIdx.x * 32, br = blockIdx.y * 32;
    int x = threadIdx.x, y = threadIdx.y;   // block (32,8)
#pragma unroll
    for (int j = 0; j < 32; j += 8)
        t[y + j][x] = in[(size_t)(br + y + j) * C + bc + x];
    __syncthreads();
#pragma unroll
    for (int j = 0; j < 32; j += 8)
        out[(size_t)(bc + y + j) * R + br + x] = f2b(t[x][y + j]);
}

// ------------- GEMM: C[M,N] = A[M,K] * B[N,K]^T (bf16 in, bf16/f32 out) -------------
// m97 structure: 128x128 tile, BK=32, 4 waves, 4x4 16x16x32 MFMA frags/wave,
// global_load_lds width-16 staging, 2 barriers per K-step.
template<int OUTF32>
__global__ __launch_bounds__(256, 2)
void gemm_bt(const unsigned short* __restrict__ A,
             const unsigned short* __restrict__ B,
             void* __restrict__ Cp, const float* __restrict__ bias,
             int M, int N, int K) {
    __shared__ unsigned short As[128 * 32];
    __shared__ unsigned short Bs[128 * 32];
    const int tid  = threadIdx.x;
    const int wave = tid >> 6;
    const int lane = tid & 63;
    const int nbn  = N >> 7;
    const int bm   = blockIdx.x / nbn;
    const int bn   = blockIdx.x - bm * nbn;

    const int lr  = lane & 15;
    const int lk8 = (lane >> 4) << 3;
    const int wr  = (wave >> 1) * 64;
    const int wc  = (wave & 1) * 64;

    const unsigned short* ag = A + (size_t)(bm * 128 + (tid >> 2)) * K + ((tid & 3) << 3);
    const unsigned short* bg = B + (size_t)(bn * 128 + (tid >> 2)) * K + ((tid & 3) << 3);
    unsigned short* asd = As + wave * 512;   // wave-uniform LDS dest
    unsigned short* bsd = Bs + wave * 512;

    f32x4 acc[4][4];
#pragma unroll
    for (int m = 0; m < 4; ++m)
#pragma unroll
        for (int n = 0; n < 4; ++n)
            acc[m][n] = (f32x4){0.f, 0.f, 0.f, 0.f};

    for (int k0 = 0; k0 < K; k0 += 32) {
        __builtin_amdgcn_global_load_lds(GLBP(ag + k0),                    LDSP(asd),        16, 0, 0);
        __builtin_amdgcn_global_load_lds(GLBP(ag + (size_t)64 * K + k0),   LDSP(asd + 2048), 16, 0, 0);
        __builtin_amdgcn_global_load_lds(GLBP(bg + k0),                    LDSP(bsd),        16, 0, 0);
        __builtin_amdgcn_global_load_lds(GLBP(bg + (size_t)64 * K + k0),   LDSP(bsd + 2048), 16, 0, 0);
        __syncthreads();
        bf16x8 af[4], bfr[4];
#pragma unroll
        for (int m = 0; m < 4; ++m)
            af[m] = *reinterpret_cast<const bf16x8*>(&As[(wr + m * 16 + lr) * 32 + lk8]);
#pragma unroll
        for (int n = 0; n < 4; ++n)
            bfr[n] = *reinterpret_cast<const bf16x8*>(&Bs[(wc + n * 16 + lr) * 32 + lk8]);
#pragma unroll
        for (int m = 0; m < 4; ++m)
#pragma unroll
            for (int n = 0; n < 4; ++n)
                acc[m][n] = __builtin_amdgcn_mfma_f32_16x16x32_bf16(af[m], bfr[n], acc[m][n], 0, 0, 0);
        __syncthreads();
    }

    const int rb = (lane >> 4) << 2;
    if (OUTF32) {
        float* C = reinterpret_cast<float*>(Cp);
#pragma unroll
        for (int m = 0; m < 4; ++m)
#pragma unroll
            for (int n = 0; n < 4; ++n) {
                const int col = bn * 128 + wc + n * 16 + lr;
                const float bv = bias[col];
#pragma unroll
                for (int r = 0; r < 4; ++r) {
                    const int row = bm * 128 + wr + m * 16 + rb + r;
                    C[(size_t)row * N + col] = acc[m][n][r] + bv;
                }
            }
    } else {
        unsigned short* C = reinterpret_cast<unsigned short*>(Cp);
#pragma unroll
        for (int m = 0; m < 4; ++m)
#pragma unroll
            for (int n = 0; n < 4; ++n) {
                const int col = bn * 128 + wc + n * 16 + lr;
#pragma unroll
                for (int r = 0; r < 4; ++r) {
                    const int row = bm * 128 + wr + m * 16 + rb + r;
                    C[(size_t)row * N + col] = f2b(acc[m][n][r]);
                }
            }
    }
}

// ------------- fused flash attention with key-length masking -------------
// grid: (B*H) * (N/64).  block 256 = 4 waves, each wave owns 16 q-rows.
// Q frags in regs; K tile [64][64+pad] and V^T tile [64][64+pad] in LDS;
// online softmax in the MFMA C/D layout; P staged bf16 via per-wave LDS.
__global__ __launch_bounds__(256, 2)
void attn_fused(const unsigned short* __restrict__ Q,   // [8192][1024]
                const unsigned short* __restrict__ KV,  // [8192][2048] (k | v)
                const int* __restrict__ lengths,
                unsigned short* __restrict__ O) {       // [8192][1024]
    __shared__ unsigned short Kl[64 * 72];
    __shared__ unsigned short Vt[64 * 72];
    __shared__ unsigned short Pl[4][16 * 72];

    const int tid  = threadIdx.x;
    const int wave = tid >> 6;
    const int lane = tid & 63;
    const int qt = blockIdx.x & 15;
    const int bh = blockIdx.x >> 4;
    const int b  = bh >> 4;
    const int h  = bh & 15;
    const int L  = lengths[b];

    const int lr  = lane & 15;
    const int lk8 = (lane >> 4) << 3;   // 0,8,16,24
    const int rb  = (lane >> 4) << 2;   // 0,4,8,12

    // Q fragments (A-operand layout: row=lane&15, k = (lane>>4)*8 within 32-slice)
    const size_t qrow = (size_t)(b * 1024 + qt * 64 + wave * 16 + lr);
    bf16x8 qf[2];
    qf[0] = *reinterpret_cast<const bf16x8*>(&Q[qrow * 1024 + h * 64 + lk8]);
    qf[1] = *reinterpret_cast<const bf16x8*>(&Q[qrow * 1024 + h * 64 + 32 + lk8]);

    f32x4 oacc[4];
#pragma unroll
    for (int nd = 0; nd < 4; ++nd) oacc[nd] = (f32x4){0.f, 0.f, 0.f, 0.f};
    float mrun[4] = {-3.0e38f, -3.0e38f, -3.0e38f, -3.0e38f};
    float lrun[4] = {0.f, 0.f, 0.f, 0.f};

    const int ntiles = (L + 63) >> 6;
    for (int t = 0; t < ntiles; ++t) {
        const int j0 = t * 64;
        __syncthreads();   // previous tile's PV done before restaging
        // stage K rows and transposed V
#pragma unroll
        for (int rep = 0; rep < 2; ++rep) {
            const int idx  = rep * 256 + tid;
            const int key  = idx >> 3;
            const int dseg = (idx & 7) << 3;
            const size_t krow = (size_t)(b * 1024 + j0 + key) * 2048 + h * 64;
            bf16x8 kv = *reinterpret_cast<const bf16x8*>(&KV[krow + dseg]);
            *reinterpret_cast<bf16x8*>(&Kl[key * 72 + dseg]) = kv;
            bf16x8 vv = *reinterpret_cast<const bf16x8*>(&KV[krow + 1024 + dseg]);
#pragma unroll
            for (int j = 0; j < 8; ++j)
                Vt[(dseg + j) * 72 + key] = (unsigned short)vv[j];
        }
        __syncthreads();

        // S = Q K^T  (per wave: 16 q-rows x 64 keys)
        f32x4 sacc[4];
#pragma unroll
        for (int n = 0; n < 4; ++n) sacc[n] = (f32x4){0.f, 0.f, 0.f, 0.f};
#pragma unroll
        for (int n = 0; n < 4; ++n) {
            bf16x8 kf0 = *reinterpret_cast<const bf16x8*>(&Kl[(n * 16 + lr) * 72 + lk8]);
            bf16x8 kf1 = *reinterpret_cast<const bf16x8*>(&Kl[(n * 16 + lr) * 72 + 32 + lk8]);
            sacc[n] = __builtin_amdgcn_mfma_f32_16x16x32_bf16(qf[0], kf0, sacc[n], 0, 0, 0);
            sacc[n] = __builtin_amdgcn_mfma_f32_16x16x32_bf16(qf[1], kf1, sacc[n], 0, 0, 0);
        }

        // scale + mask
        float sv[4][4];
#pragma unroll
        for (int n = 0; n < 4; ++n)
#pragma unroll
            for (int r = 0; r < 4; ++r) {
                const int key = j0 + n * 16 + lr;
                sv[n][r] = (key < L) ? sacc[n][r] * 0.125f : -3.0e38f;
            }

        // online softmax: row r lives in regs r of 16-lane group (lane>>4)
        float tmax[4], alpha[4], psum[4];
#pragma unroll
        for (int r = 0; r < 4; ++r) {
            float tm = fmaxf(fmaxf(sv[0][r], sv[1][r]), fmaxf(sv[2][r], sv[3][r]));
#pragma unroll
            for (int off = 1; off < 16; off <<= 1)
                tm = fmaxf(tm, __shfl_xor(tm, off));
            tmax[r] = tm;
            const float mn = fmaxf(mrun[r], tm);
            alpha[r] = __expf(mrun[r] - mn);
            mrun[r] = mn;
            psum[r] = 0.f;
        }
        float pv[4][4];
#pragma unroll
        for (int n = 0; n < 4; ++n)
#pragma unroll
            for (int r = 0; r < 4; ++r) {
                const float p = __expf(sv[n][r] - mrun[r]);
                pv[n][r] = p;
                psum[r] += p;
            }
#pragma unroll
        for (int r = 0; r < 4; ++r) {
#pragma unroll
            for (int off = 1; off < 16; off <<= 1)
                psum[r] += __shfl_xor(psum[r], off);
            lrun[r] = lrun[r] * alpha[r] + psum[r];
        }
#pragma unroll
        for (int nd = 0; nd < 4; ++nd)
#pragma unroll
            for (int r = 0; r < 4; ++r)
                oacc[nd][r] *= alpha[r];

        // P -> LDS (bf16) in A-operand-readable layout
#pragma unroll
        for (int n = 0; n < 4; ++n)
#pragma unroll
            for (int r = 0; r < 4; ++r)
                Pl[wave][(rb + r) * 72 + n * 16 + lr] = f2b(pv[n][r]);
        __syncthreads();

        // O += P V
#pragma unroll
        for (int nd = 0; nd < 4; ++nd) {
#pragma unroll
            for (int kk = 0; kk < 2; ++kk) {
                bf16x8 pf = *reinterpret_cast<const bf16x8*>(&Pl[wave][lr * 72 + kk * 32 + lk8]);
                bf16x8 vf = *reinterpret_cast<const bf16x8*>(&Vt[(nd * 16 + lr) * 72 + kk * 32 + lk8]);
                oacc[nd] = __builtin_amdgcn_mfma_f32_16x16x32_bf16(pf, vf, oacc[nd], 0, 0, 0);
            }
        }
    }

    // normalize + write
    const size_t orow = (size_t)(b * 1024 + qt * 64 + wave * 16);
#pragma unroll
    for (int r = 0; r < 4; ++r) {
        const float inv = 1.0f / lrun[r];
#pragma unroll
        for (int nd = 0; nd < 4; ++nd)
            O[(orow + rb + r) * 1024 + h * 64 + nd * 16 + lr] = f2b(oacc[nd][r] * inv);
    }
}

extern "C" void kernel_launch(void* const* d_in, const int* in_sizes, int n_in,
                              void* d_out, int out_size, void* d_ws, size_t ws_size,
                              hipStream_t stream) {
    const float* x    = (const float*)d_in[0];
    const float* ctx  = (const float*)d_in[1];
    const int*   len  = (const int*)d_in[2];
    const float* Wq   = (const float*)d_in[3];
    const float* Wkv  = (const float*)d_in[4];
    const float* Wout = (const float*)d_in[5];
    const float* bout = (const float*)d_in[6];
    float* out = (float*)d_out;

    char* w = (char*)d_ws;
    unsigned short* xb   = (unsigned short*)w; w += (size_t)8192 * 1024 * 2;
    unsigned short* cb   = (unsigned short*)w; w += (size_t)8192 * 1024 * 2;
    unsigned short* qb   = (unsigned short*)w; w += (size_t)8192 * 1024 * 2;
    unsigned short* kvb  = (unsigned short*)w; w += (size_t)8192 * 2048 * 2;
    unsigned short* aob  = (unsigned short*)w; w += (size_t)8192 * 1024 * 2;
    unsigned short* wqt  = (unsigned short*)w; w += (size_t)1024 * 1024 * 2;
    unsigned short* wkvt = (unsigned short*)w; w += (size_t)2048 * 1024 * 2;
    unsigned short* wot  = (unsigned short*)w; w += (size_t)1024 * 1024 * 2;

    cast_f32_to_bf16<<<2048, 256, 0, stream>>>(x,   xb, 8192 * 1024);
    cast_f32_to_bf16<<<2048, 256, 0, stream>>>(ctx, cb, 8192 * 1024);
    dim3 tb(32, 8);
    transpose_cast<<<dim3(32, 32), tb, 0, stream>>>(Wq,   wqt,  1024, 1024);
    transpose_cast<<<dim3(64, 32), tb, 0, stream>>>(Wkv,  wkvt, 1024, 2048);
    transpose_cast<<<dim3(32, 32), tb, 0, stream>>>(Wout, wot,  1024, 1024);

    gemm_bt<0><<<512,  256, 0, stream>>>(xb, wqt,  (void*)qb,  nullptr, 8192, 1024, 1024);
    gemm_bt<0><<<1024, 256, 0, stream>>>(cb, wkvt, (void*)kvb, nullptr, 8192, 2048, 1024);
    attn_fused<<<2048, 256, 0, stream>>>(qb, kvb, len, aob);
    gemm_bt<1><<<512,  256, 0, stream>>>(aob, wot, (void*)out, bout, 8192, 1024, 1024);
}